// Round 3
// baseline (245.864 us; speedup 1.0000x reference)
//
#include <hip/hip_runtime.h>
#include <hip/hip_cooperative_groups.h>
#include <math.h>

namespace cg = cooperative_groups;

#define NL 371
#define LUTN 3072            // 48 KB LDS LUT -> 3 blocks/CU
#define NPIX (1024*1024)
#define NB 8
#define STRESS_MAG 72000000.0f

// ---- ordered-uint encoding for float atomics (handles negatives) ----
__device__ __forceinline__ unsigned enc(float f) {
    unsigned u = __float_as_uint(f);
    return (u & 0x80000000u) ? ~u : (u | 0x80000000u);
}
__device__ __forceinline__ float dec(unsigned k) {
    unsigned u = (k & 0x80000000u) ? (k ^ 0x80000000u) : ~k;
    return __uint_as_float(u);
}

__device__ __forceinline__ void lut_interp(const float4* slut, float s,
                                           float& i0, float& i1, float& i2) {
    float t = s * (float)(LUTN - 1);
    int j = (int)t;
    j = min(j, LUTN - 2);
    float fr = t - (float)j;
    float4 A = slut[j];
    float4 B = slut[j + 1];
    i0 = fmaf(fr, B.x - A.x, A.x);
    i1 = fmaf(fr, B.y - A.y, A.y);
    i2 = fmaf(fr, B.z - A.z, A.z);
}

__global__ __launch_bounds__(256, 3) void k_fused(
    const float4* __restrict__ x, const float* __restrict__ w,
    float4* __restrict__ lutg,
    unsigned* __restrict__ minU, unsigned* __restrict__ maxU,
    unsigned* __restrict__ isoU,
    float4* __restrict__ snorm, float4* __restrict__ iso, int bpb) {
    __shared__ float4 slut[LUTN];          // 48 KB; phase-0 scratch aliases into it
    __shared__ float smA[4], smB[4];
    cg::grid_group grid = cg::this_grid();

    const int tid    = threadIdx.x;
    const int b      = blockIdx.x / bpb;   // batch
    const int bx     = blockIdx.x - b * bpb;
    const int stride = bpb * 256;

    // ---- phase 0: first LUTN/64 blocks build LUT into lutg (ws) ----
    if (blockIdx.x < (LUTN / 64)) {
        float* base = (float*)slut;        // alias LDS as scratch
        float* r0 = base;        float* r1 = base + 256;  float* r2 = base + 512;
        float* kw = base + 768;  float* w0 = kw + NL;
        float* w1 = w0 + NL;     float* w2 = w1 + NL;     // ends < 3072 floats, fits
        const float coef_rev = (float)(0.01 * 3.5e-12 / 1e-9) * STRESS_MAG; // ~2520 rev
        for (int i = tid; i < NL; i += 256) {
            float lam = 390.0f + (float)i;  // linspace(390,760,371), step 1.0
            kw[i] = coef_rev / lam;
            w0[i] = w[i * 3 + 0]; w1[i] = w[i * 3 + 1]; w2[i] = w[i * 3 + 2];
        }
        __syncthreads();
        int jj = tid & 63, part = tid >> 6;
        int j  = blockIdx.x * 64 + jj;
        float s = (float)j * (1.0f / (float)(LUTN - 1));
        float a0 = 0.f, a1 = 0.f, a2 = 0.f;
        for (int i = part; i < NL; i += 4) {
            float r = kw[i] * s;               // revolutions, <= ~6.5
            r = r - floorf(r);
            float c = __builtin_amdgcn_cosf(r); // v_cos_f32: cos(2*pi*r)
            float t = fmaf(-0.5f, c, 0.5f);
            a0 = fmaf(w0[i], t, a0); a1 = fmaf(w1[i], t, a1); a2 = fmaf(w2[i], t, a2);
        }
        r0[tid] = a0; r1[tid] = a1; r2[tid] = a2;  // disjoint from kw/w* regions
        __syncthreads();
        if (part == 0) {
            float b0 = (r0[jj] + r0[jj + 64]) + (r0[jj + 128] + r0[jj + 192]);
            float b1 = (r1[jj] + r1[jj + 64]) + (r1[jj + 128] + r1[jj + 192]);
            float b2 = (r2[jj] + r2[jj + 64]) + (r2[jj + 128] + r2[jj + 192]);
            lutg[j] = make_float4(b0, b1, b2, 0.0f);
        }
    }

    // ---- phase A: per-batch min/max of input ----
    const float4* p = x + (size_t)b * (NPIX / 4);
    float mn = 3.4e38f, mx = -3.4e38f;
    #pragma unroll 2
    for (int i = bx * 256 + tid; i < NPIX / 4; i += stride) {
        float4 v = p[i];
        mn = fminf(mn, fminf(fminf(v.x, v.y), fminf(v.z, v.w)));
        mx = fmaxf(mx, fmaxf(fmaxf(v.x, v.y), fmaxf(v.z, v.w)));
    }
    for (int off = 32; off >= 1; off >>= 1) {
        mn = fminf(mn, __shfl_down(mn, off));
        mx = fmaxf(mx, __shfl_down(mx, off));
    }
    int wid = tid >> 6;
    if ((tid & 63) == 0) { smA[wid] = mn; smB[wid] = mx; }
    __syncthreads();
    if (tid == 0) {
        for (int k = 1; k < 4; ++k) { mn = fminf(mn, smA[k]); mx = fmaxf(mx, smB[k]); }
        atomicMin(minU + b, enc(mn));
        atomicMax(maxU + b, enc(mx));
    }

    grid.sync();

    // ---- load LUT to LDS; fetch min/max (device-scope) ----
    for (int i = tid; i < LUTN; i += 256) slut[i] = lutg[i];
    float mnv = dec(__hip_atomic_load(minU + b, __ATOMIC_RELAXED, __HIP_MEMORY_SCOPE_AGENT));
    float mxv = dec(__hip_atomic_load(maxU + b, __ATOMIC_RELAXED, __HIP_MEMORY_SCOPE_AGENT));
    float inv = 1.0f / (mxv - mnv);
    __syncthreads();

    // ---- phase B: write snorm, reduce per-batch iso max ----
    float4* q = snorm + (size_t)b * (NPIX / 4);
    float m = 0.0f;
    for (int i = bx * 256 + tid; i < NPIX / 4; i += stride) {
        float4 v = p[i];
        float4 s;
        s.x = (v.x - mnv) * inv; s.y = (v.y - mnv) * inv;
        s.z = (v.z - mnv) * inv; s.w = (v.w - mnv) * inv;
        q[i] = s;
        float i0, i1, i2;
        lut_interp(slut, s.x, i0, i1, i2);
        m = fmaxf(m, fmaxf(fmaxf(i0, i1), i2));
        lut_interp(slut, s.y, i0, i1, i2);
        m = fmaxf(m, fmaxf(fmaxf(i0, i1), i2));
        lut_interp(slut, s.z, i0, i1, i2);
        m = fmaxf(m, fmaxf(fmaxf(i0, i1), i2));
        lut_interp(slut, s.w, i0, i1, i2);
        m = fmaxf(m, fmaxf(fmaxf(i0, i1), i2));
    }
    for (int off = 32; off >= 1; off >>= 1)
        m = fmaxf(m, __shfl_down(m, off));
    if ((tid & 63) == 0) smA[wid] = m;
    __syncthreads();
    if (tid == 0) {
        for (int k = 1; k < 4; ++k) m = fmaxf(m, smA[k]);
        atomicMax(isoU + b, enc(m));
    }

    grid.sync();

    // ---- phase C: re-read snorm (L1/L2-warm), interp, scale, write iso ----
    float invIso = 1.0f / dec(__hip_atomic_load(isoU + b, __ATOMIC_RELAXED,
                                                __HIP_MEMORY_SCOPE_AGENT));
    float4* q0 = iso + (size_t)(b * 3 + 0) * (NPIX / 4);
    float4* q1 = iso + (size_t)(b * 3 + 1) * (NPIX / 4);
    float4* q2 = iso + (size_t)(b * 3 + 2) * (NPIX / 4);
    for (int i = bx * 256 + tid; i < NPIX / 4; i += stride) {
        float4 s = p ? q[i] : q[i];
        float4 r0v, r1v, r2v;
        float i0, i1, i2;
        lut_interp(slut, s.x, i0, i1, i2);
        r0v.x = i0 * invIso; r1v.x = i1 * invIso; r2v.x = i2 * invIso;
        lut_interp(slut, s.y, i0, i1, i2);
        r0v.y = i0 * invIso; r1v.y = i1 * invIso; r2v.y = i2 * invIso;
        lut_interp(slut, s.z, i0, i1, i2);
        r0v.z = i0 * invIso; r1v.z = i1 * invIso; r2v.z = i2 * invIso;
        lut_interp(slut, s.w, i0, i1, i2);
        r0v.w = i0 * invIso; r1v.w = i1 * invIso; r2v.w = i2 * invIso;
        q0[i] = r0v; q1[i] = r1v; q2[i] = r2v;
    }
}

extern "C" void kernel_launch(void* const* d_in, const int* in_sizes, int n_in,
                              void* d_out, int out_size, void* d_ws, size_t ws_size,
                              hipStream_t stream) {
    const float4* x = (const float4*)d_in[0];   // [8,1,1024,1024] f32
    const float*  w = (const float*)d_in[1];    // [371,3] f32

    float* out    = (float*)d_out;
    float4* iso   = (float4*)out;                               // 8*3*1M f32
    float4* snorm = (float4*)(out + (size_t)NB * 3 * NPIX);     // 8*1M f32

    float4*   lutg = (float4*)d_ws;                             // 48 KB
    unsigned* minU = (unsigned*)((char*)d_ws + (size_t)LUTN * 16);
    unsigned* maxU = minU + NB;
    unsigned* isoU = maxU + NB;

    // init atomic slots (capture-safe async memsets)
    hipMemsetAsync(minU, 0xFF, NB * sizeof(unsigned), stream);
    hipMemsetAsync(maxU, 0, 2 * NB * sizeof(unsigned), stream);  // maxU + isoU

    int maxBlk = 0;
    hipOccupancyMaxActiveBlocksPerMultiprocessor(&maxBlk, (const void*)k_fused, 256, 0);
    if (maxBlk < 1) maxBlk = 1;
    if (maxBlk > 3) maxBlk = 3;
    int ncu = 0;
    hipDeviceGetAttribute(&ncu, hipDeviceAttributeMultiprocessorCount, 0);
    if (ncu <= 0) ncu = 256;
    int bpb  = (maxBlk * ncu) / NB;
    if (bpb < 8) bpb = 8;
    int grid = bpb * NB;

    void* args[] = {(void*)&x, (void*)&w, (void*)&lutg, (void*)&minU,
                    (void*)&maxU, (void*)&isoU, (void*)&snorm, (void*)&iso,
                    (void*)&bpb};
    hipLaunchCooperativeKernel((const void*)k_fused, dim3(grid), dim3(256),
                               args, 0, stream);
}

// Round 4
// 94.341 us; speedup vs baseline: 2.6061x; 2.6061x over previous
//
#include <hip/hip_runtime.h>
#include <math.h>

#define NL 371
#define LUTN 3072            // 48 KB LDS LUT -> 3 blocks/CU at 512 thr = 24 waves/CU
#define NPIX (1024*1024)
#define NB 8
#define STRESS_MAG 72000000.0f

typedef float v4f __attribute__((ext_vector_type(4)));

// ---- ordered-uint encoding for float atomics (handles negatives) ----
__device__ __forceinline__ unsigned enc(float f) {
    unsigned u = __float_as_uint(f);
    return (u & 0x80000000u) ? ~u : (u | 0x80000000u);
}
__device__ __forceinline__ float dec(unsigned k) {
    unsigned u = (k & 0x80000000u) ? (k ^ 0x80000000u) : ~k;
    return __uint_as_float(u);
}

__device__ __forceinline__ void store_nt(float4* p, float4 v) {
    __builtin_nontemporal_store(*(const v4f*)&v, (v4f*)p);
}

// Build LUT: f_c(s) = sum_i w[i][c] * 0.5 * (1 - cos(2*pi * k_rev[i] * s))
// 48 blocks x 256 threads; each block: 64 j-values x 4 lambda-partitions.
__global__ __launch_bounds__(256) void k_lut(const float* __restrict__ w,
                                             float4* __restrict__ lut) {
    __shared__ float kw[NL], w0[NL], w1[NL], w2[NL];
    const float coef_rev = (float)(0.01 * 3.5e-12 / 1e-9) * STRESS_MAG; // ~2520 rev
    for (int i = threadIdx.x; i < NL; i += blockDim.x) {
        float lam = 390.0f + (float)i;      // linspace(390,760,371), step 1.0
        kw[i] = coef_rev / lam;
        w0[i] = w[i * 3 + 0];
        w1[i] = w[i * 3 + 1];
        w2[i] = w[i * 3 + 2];
    }
    __syncthreads();

    int jj   = threadIdx.x & 63;
    int part = threadIdx.x >> 6;            // 0..3 lambda partition
    int j    = blockIdx.x * 64 + jj;
    float s  = (float)j * (1.0f / (float)(LUTN - 1));

    float a0 = 0.f, a1 = 0.f, a2 = 0.f;
    for (int i = part; i < NL; i += 4) {
        float r = kw[i] * s;                // revolutions, <= ~6.5
        r = r - floorf(r);                  // reduce to [0,1)
        float c = __builtin_amdgcn_cosf(r); // v_cos_f32: cos(2*pi*r)
        float t = fmaf(-0.5f, c, 0.5f);     // 0.5*(1-c)
        a0 = fmaf(w0[i], t, a0);
        a1 = fmaf(w1[i], t, a1);
        a2 = fmaf(w2[i], t, a2);
    }

    __shared__ float r0[256], r1[256], r2[256];
    r0[threadIdx.x] = a0; r1[threadIdx.x] = a1; r2[threadIdx.x] = a2;
    __syncthreads();
    if (part == 0) {
        a0 = (r0[jj] + r0[jj + 64]) + (r0[jj + 128] + r0[jj + 192]);
        a1 = (r1[jj] + r1[jj + 64]) + (r1[jj + 128] + r1[jj + 192]);
        a2 = (r2[jj] + r2[jj + 64]) + (r2[jj + 128] + r2[jj + 192]);
        lut[j] = make_float4(a0, a1, a2, 0.0f);
    }
}

__global__ __launch_bounds__(512, 8) void k_minmax(const float4* __restrict__ x,
                                                   unsigned* __restrict__ minU,
                                                   unsigned* __restrict__ maxU) {
    int b = blockIdx.y;
    const float4* p = x + (size_t)b * (NPIX / 4);
    float mn = 3.4e38f, mx = -3.4e38f;
    for (int i = blockIdx.x * blockDim.x + threadIdx.x; i < NPIX / 4;
         i += gridDim.x * blockDim.x) {
        float4 v = p[i];
        mn = fminf(mn, fminf(fminf(v.x, v.y), fminf(v.z, v.w)));
        mx = fmaxf(mx, fmaxf(fmaxf(v.x, v.y), fmaxf(v.z, v.w)));
    }
    for (int off = 32; off >= 1; off >>= 1) {
        mn = fminf(mn, __shfl_down(mn, off));
        mx = fmaxf(mx, __shfl_down(mx, off));
    }
    __shared__ float smn[8], smx[8];
    int wid = threadIdx.x >> 6;
    if ((threadIdx.x & 63) == 0) { smn[wid] = mn; smx[wid] = mx; }
    __syncthreads();
    if (threadIdx.x == 0) {
        for (int w = 1; w < 8; ++w) { mn = fminf(mn, smn[w]); mx = fmaxf(mx, smx[w]); }
        atomicMin(&minU[b], enc(mn));
        atomicMax(&maxU[b], enc(mx));
    }
}

__device__ __forceinline__ void lut_interp(const float4* slut, float s,
                                           float& i0, float& i1, float& i2) {
    float t = s * (float)(LUTN - 1);
    int j = (int)t;
    j = min(j, LUTN - 2);
    float fr = t - (float)j;
    float4 A = slut[j];
    float4 B = slut[j + 1];
    i0 = fmaf(fr, B.x - A.x, A.x);
    i1 = fmaf(fr, B.y - A.y, A.y);
    i2 = fmaf(fr, B.z - A.z, A.z);
}

// Pass 1: write stress_nomal (temporal, re-read by pass2), per-batch iso max
__global__ __launch_bounds__(512, 6) void k_pass1(const float4* __restrict__ x,
                                                  const float4* __restrict__ lut,
                                                  const unsigned* __restrict__ minU,
                                                  const unsigned* __restrict__ maxU,
                                                  unsigned* __restrict__ isoU,
                                                  float4* __restrict__ snorm) {
    __shared__ float4 slut[LUTN];   // 48 KB
    for (int i = threadIdx.x; i < LUTN; i += blockDim.x) slut[i] = lut[i];
    __syncthreads();
    int b = blockIdx.y;
    float mn  = dec(minU[b]);
    float inv = 1.0f / (dec(maxU[b]) - mn);
    const float4* p = x + (size_t)b * (NPIX / 4);
    float4* q = snorm + (size_t)b * (NPIX / 4);
    float m = 0.0f;
    #pragma unroll 2
    for (int i = blockIdx.x * blockDim.x + threadIdx.x; i < NPIX / 4;
         i += gridDim.x * blockDim.x) {
        float4 v = p[i];
        float4 s;
        s.x = (v.x - mn) * inv; s.y = (v.y - mn) * inv;
        s.z = (v.z - mn) * inv; s.w = (v.w - mn) * inv;
        q[i] = s;
        float i0, i1, i2;
        lut_interp(slut, s.x, i0, i1, i2);
        m = fmaxf(m, fmaxf(fmaxf(i0, i1), i2));
        lut_interp(slut, s.y, i0, i1, i2);
        m = fmaxf(m, fmaxf(fmaxf(i0, i1), i2));
        lut_interp(slut, s.z, i0, i1, i2);
        m = fmaxf(m, fmaxf(fmaxf(i0, i1), i2));
        lut_interp(slut, s.w, i0, i1, i2);
        m = fmaxf(m, fmaxf(fmaxf(i0, i1), i2));
    }
    for (int off = 32; off >= 1; off >>= 1)
        m = fmaxf(m, __shfl_down(m, off));
    __shared__ float sm[8];
    int wid = threadIdx.x >> 6;
    if ((threadIdx.x & 63) == 0) sm[wid] = m;
    __syncthreads();
    if (threadIdx.x == 0) {
        for (int w = 1; w < 8; ++w) m = fmaxf(m, sm[w]);
        atomicMax(&isoU[b], enc(m));
    }
}

// Pass 2: read snorm (L2-warm), interp, scale, nontemporal-write iso planes
__global__ __launch_bounds__(512, 6) void k_pass2(const float4* __restrict__ snorm,
                                                  const float4* __restrict__ lut,
                                                  const unsigned* __restrict__ isoU,
                                                  float4* __restrict__ iso) {
    __shared__ float4 slut[LUTN];   // 48 KB
    for (int i = threadIdx.x; i < LUTN; i += blockDim.x) slut[i] = lut[i];
    __syncthreads();
    int b = blockIdx.y;
    float invIso = 1.0f / dec(isoU[b]);
    const float4* p = snorm + (size_t)b * (NPIX / 4);
    float4* q0 = iso + (size_t)(b * 3 + 0) * (NPIX / 4);
    float4* q1 = iso + (size_t)(b * 3 + 1) * (NPIX / 4);
    float4* q2 = iso + (size_t)(b * 3 + 2) * (NPIX / 4);
    #pragma unroll 2
    for (int i = blockIdx.x * blockDim.x + threadIdx.x; i < NPIX / 4;
         i += gridDim.x * blockDim.x) {
        float4 s = p[i];
        float4 r0, r1, r2;
        float i0, i1, i2;
        lut_interp(slut, s.x, i0, i1, i2);
        r0.x = i0 * invIso; r1.x = i1 * invIso; r2.x = i2 * invIso;
        lut_interp(slut, s.y, i0, i1, i2);
        r0.y = i0 * invIso; r1.y = i1 * invIso; r2.y = i2 * invIso;
        lut_interp(slut, s.z, i0, i1, i2);
        r0.z = i0 * invIso; r1.z = i1 * invIso; r2.z = i2 * invIso;
        lut_interp(slut, s.w, i0, i1, i2);
        r0.w = i0 * invIso; r1.w = i1 * invIso; r2.w = i2 * invIso;
        store_nt(&q0[i], r0);
        store_nt(&q1[i], r1);
        store_nt(&q2[i], r2);
    }
}

extern "C" void kernel_launch(void* const* d_in, const int* in_sizes, int n_in,
                              void* d_out, int out_size, void* d_ws, size_t ws_size,
                              hipStream_t stream) {
    const float4* x = (const float4*)d_in[0];   // [8,1,1024,1024] f32
    const float*  w = (const float*)d_in[1];    // [371,3] f32

    float* out    = (float*)d_out;
    float4* iso   = (float4*)out;                               // 8*3*1M f32
    float4* snorm = (float4*)(out + (size_t)NB * 3 * NPIX);     // 8*1M f32

    float4*   lutg = (float4*)d_ws;                             // 48 KB
    unsigned* minU = (unsigned*)((char*)d_ws + (size_t)LUTN * 16);
    unsigned* maxU = minU + NB;
    unsigned* isoU = maxU + NB;

    // init atomic slots (capture-safe async memsets); layout is contiguous
    hipMemsetAsync(minU, 0xFF, NB * sizeof(unsigned), stream);
    hipMemsetAsync(maxU, 0, 2 * NB * sizeof(unsigned), stream);  // maxU + isoU

    k_lut<<<dim3(LUTN / 64), dim3(256), 0, stream>>>(w, lutg);
    k_minmax<<<dim3(128, NB), dim3(512), 0, stream>>>(x, minU, maxU);
    k_pass1<<<dim3(96, NB), dim3(512), 0, stream>>>(x, lutg, minU, maxU, isoU, snorm);
    k_pass2<<<dim3(96, NB), dim3(512), 0, stream>>>(snorm, lutg, isoU, iso);
}